// Round 9
// baseline (85.606 us; speedup 1.0000x reference)
//
#include <hip/hip_runtime.h>
#include <hip/hip_bf16.h>

typedef __bf16 bf16x8 __attribute__((ext_vector_type(8)));
typedef float  f32x4  __attribute__((ext_vector_type(4)));

static constexpr int D     = 128;
static constexpr int BATCH = 4096;
static constexpr int N     = 8192;
static constexpr int BT    = 128;               // tile
static constexpr int NT    = N / BT;            // 64
static constexpr int TRI   = NT * (NT + 1) / 2; // 2080

__device__ __forceinline__ void load_lds16(const void* g, void* l) {
    __builtin_amdgcn_global_load_lds(
        (const __attribute__((address_space(1))) unsigned int*)g,
        (__attribute__((address_space(3))) unsigned int*)l, 16, 0, 0);
}

#define WAITV(n) do { asm volatile("s_waitcnt vmcnt(" #n ")" ::: "memory"); \
                      __builtin_amdgcn_sched_barrier(0); } while (0)
#define BAR()    do { __builtin_amdgcn_s_barrier(); \
                      __builtin_amdgcn_sched_barrier(0); } while (0)
#define LGKM0()  do { asm volatile("s_waitcnt lgkmcnt(0)" ::: "memory"); \
                      __builtin_amdgcn_sched_barrier(0); } while (0)

// ---------------- prep: build Apack (fragment-order) + Bpack (stage-order) + norms + diag ----------------
// Apack: byte(row, g=chunk16) = (row>>4)*4096 + g*256 + (row&15)*16   (g in 0..15)
// Bpack: panel p=row>>7, pair=(row>>1)&63, k=row&1, ph=g>>2, c=g&3, u=((k<<2)|c)^(pair&7)
//        byte = p*32768 + ph*8192 + (pair*8+u)*16    (exact LDS image per phase, bank-bijective)
__global__ __launch_bounds__(256) void prep_kernel(const float* __restrict__ f,
                                                   unsigned short* __restrict__ Apack,
                                                   unsigned short* __restrict__ Bpack,
                                                   float* __restrict__ norms,
                                                   float* __restrict__ diag,
                                                   float* __restrict__ out) {
    if (blockIdx.x == 0 && threadIdx.x == 0) out[0] = 0.f;
    const int w = threadIdx.x >> 6, lane = threadIdx.x & 63;
    const int i = blockIdx.x * 4 + w;                 // 0..4095
    const float2 va = *(const float2*)(f + (size_t)i * D + lane * 2);
    const float2 vb = *(const float2*)(f + (size_t)(i + BATCH) * D + lane * 2);
    union { __bf16 h[2]; unsigned int u; } pa, pb;
    pa.h[0] = (__bf16)va.x; pa.h[1] = (__bf16)va.y;
    pb.h[0] = (__bf16)vb.x; pb.h[1] = (__bf16)vb.y;

    const int g   = lane >> 2;            // 16B chunk within row
    const int off = (lane & 3) * 4;       // byte within chunk
    auto store2 = [&](int row, unsigned int bits) {
        char* ap = (char*)Apack + ((size_t)(row >> 4)) * 4096 + g * 256 + (row & 15) * 16 + off;
        *(unsigned int*)ap = bits;
        const int pair = (row >> 1) & 63, k = row & 1;
        const int ph = g >> 2, c = g & 3;
        const int u = ((k << 2) | c) ^ (pair & 7);
        char* bp = (char*)Bpack + (size_t)(row >> 7) * 32768 + ph * 8192 + (pair * 8 + u) * 16 + off;
        *(unsigned int*)bp = bits;
    };
    store2(i, pa.u);
    store2(i + BATCH, pb.u);

    float na = va.x * va.x + va.y * va.y;
    float nb = vb.x * vb.x + vb.y * vb.y;
    const float dx = va.x - vb.x, dy = va.y - vb.y;
    float dd = dx * dx + dy * dy;
    #pragma unroll
    for (int m = 1; m <= 32; m <<= 1) {
        na += __shfl_xor(na, m); nb += __shfl_xor(nb, m); dd += __shfl_xor(dd, m);
    }
    if (lane == 0) {
        norms[i] = na; norms[i + BATCH] = nb;
        diag[i] = 1.f / (dd + 1.f);                   // exact fp32 cauchy diag of sim_ab
    }
}

// ---------------- 128x128 tile: A->VGPR direct, B 4-phase dbuf counted-vmcnt pipeline ----------------
// P[t][k][0..127]: k<=t row-partials of tile(t,k); k>t col-partials of tile(k,t). Exact-once writes.
__global__ __launch_bounds__(256, 4) void tile_kernel(const unsigned short* __restrict__ Apack,
                                                      const unsigned short* __restrict__ Bpack,
                                                      const float* __restrict__ norms,
                                                      float* __restrict__ P) {
    // XCD-chunked bijective swizzle (2080 % 8 == 0)
    const int bid = blockIdx.x;
    const int id = (bid & 7) * (TRI / 8) + (bid >> 3);
    int ti = (int)((sqrtf(8.f * (float)id + 1.f) - 1.f) * 0.5f);
    while ((ti + 1) * (ti + 2) / 2 <= id) ++ti;
    while (ti * (ti + 1) / 2 > id) --ti;
    const int tj = id - ti * (ti + 1) / 2;
    const bool diagblk = (ti == tj);

    __shared__ __align__(16) unsigned char Bs[2][8192];   // double-buffered 8KB B phase
    __shared__ float colbuf[BT];

    const int tid = threadIdx.x, wv = tid >> 6, lane = tid & 63;
    const int lr = lane & 15, hk = lane >> 4;
    if (tid < BT) colbuf[tid] = 0.f;

    const char* Bb = (const char*)Bpack + (size_t)tj * 32768;
    const char* Ab = (const char*)Apack + (size_t)(ti * 8 + wv * 2) * 4096;

    f32x4 acc[2][8];
    #pragma unroll
    for (int i = 0; i < 2; ++i)
        #pragma unroll
        for (int j = 0; j < 8; ++j)
            acc[i][j] = (f32x4){0.f, 0.f, 0.f, 0.f};

    // stage phase PH of B into Bs[PH&1]: 2 gl_lds/thread, contiguous src
    #define STAGE(PH) do { \
        load_lds16(Bb + (PH) * 8192 + tid * 16,        &Bs[(PH) & 1][(tid >> 6) * 1024]); \
        load_lds16(Bb + (PH) * 8192 + 4096 + tid * 16, &Bs[(PH) & 1][4096 + (tid >> 6) * 1024]); \
    } while (0)

    // A fragments for phase I (2 global dwordx4 loads, fragment-ordered -> coalesced)
    #define AV_LOAD(AV, I) do { \
        AV[0] = *(const bf16x8*)(Ab +        ((I) * 4 + hk) * 256 + lr * 16); \
        AV[1] = *(const bf16x8*)(Ab + 4096 + ((I) * 4 + hk) * 256 + lr * 16); \
    } while (0)

    // read 8 B fragments for phase PH from LDS (bank-bijective layout)
    #define BV_READ(BV, PH) do { \
        const int u_ = (((lr & 1) << 2) | hk) ^ ((lr >> 1) & 7); \
        const int b_ = (lr >> 1) * 128 + u_ * 16; \
        _Pragma("unroll") \
        for (int fj = 0; fj < 8; ++fj) \
            BV[fj] = *(const bf16x8*)&Bs[(PH) & 1][fj * 1024 + b_]; \
    } while (0)

    #define MFMA_PH(AV, BV) do { \
        _Pragma("unroll") \
        for (int fj = 0; fj < 8; ++fj) { \
            acc[0][fj] = __builtin_amdgcn_mfma_f32_16x16x32_bf16(AV[0], BV[fj], acc[0][fj], 0, 0, 0); \
            acc[1][fj] = __builtin_amdgcn_mfma_f32_16x16x32_bf16(AV[1], BV[fj], acc[1][fj], 0, 0, 0); \
        } \
    } while (0)

    bf16x8 av0[2], av1[2], av2[2], av3[2];

    // ---- prologue: 2 phases in flight (8 vmem/thread) ----
    STAGE(0); AV_LOAD(av0, 0);
    STAGE(1); AV_LOAD(av1, 1);
    WAITV(4); BAR();                       // S0+A0 landed, visible

    { bf16x8 bv[8];                        // phase 0
      BV_READ(bv, 0); LGKM0(); BAR();     // buf0 free for reuse
      STAGE(2); AV_LOAD(av2, 2);
      MFMA_PH(av0, bv);
    }
    WAITV(4); BAR();                       // S1+A1 landed

    { bf16x8 bv[8];                        // phase 1
      BV_READ(bv, 1); LGKM0(); BAR();
      STAGE(3); AV_LOAD(av3, 3);
      MFMA_PH(av1, bv);
    }
    WAITV(4); BAR();                       // S2+A2 landed

    { bf16x8 bv[8];                        // phase 2
      BV_READ(bv, 2); LGKM0(); BAR();
      MFMA_PH(av2, bv);
    }
    WAITV(0); BAR();                       // S3+A3 landed

    { bf16x8 bv[8];                        // phase 3
      BV_READ(bv, 3); LGKM0();
      MFMA_PH(av3, bv);
    }

    // ---- epilogue: sim transform + in-wave row sums + LDS-combined col partials ----
    float colN[8];
    #pragma unroll
    for (int fj = 0; fj < 8; ++fj)
        colN[fj] = norms[tj * BT + fj * 16 + lr];

    float* PR = P + ((size_t)ti * NT + tj) * BT;
    #pragma unroll
    for (int fi = 0; fi < 2; ++fi) {
        const int lrow = wv * 32 + fi * 16 + hk * 4;          // + r
        const f32x4 rN = *(const f32x4*)(norms + ti * BT + lrow);
        f32x4 rs = (f32x4){0.f, 0.f, 0.f, 0.f};
        #pragma unroll
        for (int fj = 0; fj < 8; ++fj) {
            const int lcol = fj * 16 + lr;
            #pragma unroll
            for (int r = 0; r < 4; ++r) {
                float sq = rN[r] + colN[fj] - 2.f * acc[fi][fj][r];
                sq = fmaxf(sq, 0.f);
                float sim = __builtin_amdgcn_rcpf(sq + 1.f);
                if (diagblk && (lrow + r == lcol)) sim = 0.f;  // self-mask
                rs[r] += sim;
                acc[fi][fj][r] = sim;
            }
        }
        #pragma unroll
        for (int r = 0; r < 4; ++r) {
            rs[r] += __shfl_xor(rs[r], 1);
            rs[r] += __shfl_xor(rs[r], 2);
            rs[r] += __shfl_xor(rs[r], 4);
            rs[r] += __shfl_xor(rs[r], 8);
        }
        if (lr == 0)
            *(f32x4*)(PR + lrow) = rs;                         // exact-once row writes
    }

    if (!diagblk) {
        #pragma unroll
        for (int fj = 0; fj < 8; ++fj) {
            float cs = 0.f;
            #pragma unroll
            for (int fi = 0; fi < 2; ++fi)
                #pragma unroll
                for (int r = 0; r < 4; ++r)
                    cs += acc[fi][fj][r];
            cs += __shfl_xor(cs, 16);
            cs += __shfl_xor(cs, 32);
            if (hk == 0)
                atomicAdd(&colbuf[fj * 16 + lr], cs);
        }
        __syncthreads();
        if (tid < BT)
            P[((size_t)tj * NT + ti) * BT + tid] = colbuf[tid]; // exact-once col writes
    }
    #undef STAGE
    #undef AV_LOAD
    #undef BV_READ
    #undef MFMA_PH
}

// ---------------- finalize: uniform 64-slot sum per row, logs, scalar ----------------
__global__ __launch_bounds__(128) void finalize_kernel(const float* __restrict__ P,
                                                       const float* __restrict__ diag,
                                                       float* __restrict__ out) {
    const int t = blockIdx.x;            // 64 row-panels
    const int r = threadIdx.x;           // 128 rows per panel
    const float* base = P + (size_t)t * NT * BT + r;
    float s = 0.f;
    #pragma unroll 8
    for (int k = 0; k < NT; ++k) s += base[k * BT];
    const int i = t * BT + r;
    float term = 0.5f * __logf(s);
    if (i >= BATCH) term -= __logf(diag[i - BATCH]);
    #pragma unroll
    for (int m = 1; m <= 32; m <<= 1) term += __shfl_xor(term, m);
    if ((threadIdx.x & 63) == 0)
        atomicAdd(out, term / (float)BATCH);
}

extern "C" void kernel_launch(void* const* d_in, const int* in_sizes, int n_in,
                              void* d_out, int out_size, void* d_ws, size_t ws_size,
                              hipStream_t stream) {
    const float* feat = (const float*)d_in[0];
    char* ws = (char*)d_ws;
    // ws layout: Apack 2MB @0 | Bpack 2MB @2MB | norms 32KB @4MB | diag 16KB | P 2MB
    unsigned short* Apack = (unsigned short*)ws;
    unsigned short* Bpack = (unsigned short*)(ws + (2u << 20));
    float* norms = (float*)(ws + (4u << 20));
    float* diag  = (float*)(ws + (4u << 20) + 32768);
    float* P     = (float*)(ws + (4u << 20) + 49152);
    float* out   = (float*)d_out;

    prep_kernel<<<BATCH / 4, 256, 0, stream>>>(feat, Apack, Bpack, norms, diag, out);
    tile_kernel<<<TRI, 256, 0, stream>>>(Apack, Bpack, norms, P);
    finalize_kernel<<<NT, 128, 0, stream>>>(P, diag, out);
}